// Round 3
// baseline (529.865 us; speedup 1.0000x reference)
//
#include <hip/hip_runtime.h>

// TernaryLinear: out = x @ (sign(W1)-sign(W2)).T + (b1-b2)
// M=8192 tokens, N=4096 out, K=4096 in. One f16-MFMA GEMM after folding.
//
// GEMM: 256x256 tile, BK=64, 512 threads = 8 waves (2M x 4N), 4 phases/K-tile,
// ONE barrier per phase. Frag ds_reads are software-pipelined one phase ahead
// (issued between MFMA sub-clusters, reusing dead register slots). Staging is
// 2 K-tiles deep (16 gloads in flight max), counted vmcnt(6) gate at end of
// p2 so the K-tile-boundary frag reads overlap p3's MFMAs. XOR swizzle
// (chunk ^= row&7) on global source + ds_read side; XCD-bijective swizzle.

#define DIM_K 4096
#define DIM_N 4096
#define DIM_M 8192

typedef _Float16 f16x8 __attribute__((ext_vector_type(8)));
typedef float    f32x4 __attribute__((ext_vector_type(4)));

// ---------------- fused conversion kernel ----------------

__device__ __forceinline__ float signdiff(float a, float b) {
    const float sa = (float)((a > 0.f) - (a < 0.f));
    const float sb = (float)((b > 0.f) - (b < 0.f));
    return sa - sb;
}

__global__ void cvt_fused(const float4* __restrict__ x,
                          const float4* __restrict__ w1,
                          const float4* __restrict__ w2,
                          f16x8* __restrict__ xh,
                          f16x8* __restrict__ wh) {
    const int XU = DIM_M * DIM_K / 8;           // 4194304
    const int TU = XU + DIM_N * DIM_K / 8;      // 6291456
    const int stride = gridDim.x * blockDim.x;
    for (int u = blockIdx.x * blockDim.x + threadIdx.x; u < TU; u += stride) {
        if (u < XU) {
            const float4 a = x[2 * u], b = x[2 * u + 1];
            f16x8 h;
            h[0] = (_Float16)a.x; h[1] = (_Float16)a.y;
            h[2] = (_Float16)a.z; h[3] = (_Float16)a.w;
            h[4] = (_Float16)b.x; h[5] = (_Float16)b.y;
            h[6] = (_Float16)b.z; h[7] = (_Float16)b.w;
            xh[u] = h;
        } else {
            const int v = u - XU;
            const float4 a1 = w1[2 * v], b1 = w1[2 * v + 1];
            const float4 a2 = w2[2 * v], b2 = w2[2 * v + 1];
            f16x8 h;
            h[0] = (_Float16)signdiff(a1.x, a2.x);
            h[1] = (_Float16)signdiff(a1.y, a2.y);
            h[2] = (_Float16)signdiff(a1.z, a2.z);
            h[3] = (_Float16)signdiff(a1.w, a2.w);
            h[4] = (_Float16)signdiff(b1.x, b2.x);
            h[5] = (_Float16)signdiff(b1.y, b2.y);
            h[6] = (_Float16)signdiff(b1.z, b2.z);
            h[7] = (_Float16)signdiff(b1.w, b2.w);
            wh[v] = h;
        }
    }
}

// ---------------- GEMM ----------------
// Per K-tile (cur = kt&1; staging targets kt+2 -> buffer cur):
//  p0: [drain: b0,aLo,aHi ready] issue b1(cur);  MFMA acc[0][0] (aLo,aHi x b0)
//  p1: [drain: b1]   MFMA acc[0][1] sub(aLo);  reload aLo<-blk1;
//                    MFMA sub(aHi); reload aHi<-blk1;  stage A0,B0(kt+2)
//  p2: [drain: aLo',aHi'] MFMA acc[1][0];  stage B1(kt+2);  vmcnt(6)  <- gate:
//                    all of kt+1's 8 staging loads landed after this barrier
//  p3: issue b0(nxt); MFMA acc[1][1] sub(aLo'); issue aLo(nxt);
//                    MFMA sub(aHi'); issue aHi(nxt); stage A1(kt+2)
// Register slots are reused across reloads only after their last MFMA use
// (compiler-visible disjoint lifetimes -> same ~120 VGPR as before).
// vmcnt ledger (per wave): enter p0 with 8 outstanding (all of kt+1);
// p1 +4 = 12; p2 +2 = 14, gate vmcnt(6) drains kt+1's 8; p3 +2 = 8. Induction.

__global__ __launch_bounds__(512, 2) void ternary_gemm(
    const _Float16* __restrict__ Xh, const _Float16* __restrict__ Wh,
    const float* __restrict__ B1, const float* __restrict__ B2,
    float* __restrict__ C) {
    __shared__ __align__(16) char smem[131072];
    // A buffers at 0 / 32K; B buffers at 64K / 96K. Buffer = [256][64] f16,
    // row stride 128 B, physical chunk = logical chunk ^ (row&7).

    const int tid  = threadIdx.x;
    const int wave = tid >> 6;
    const int lane = tid & 63;
    const int wm = wave >> 2;      // 0..1
    const int wn = wave & 3;       // 0..3
    const int q  = lane >> 4;      // 0..3
    const int r  = lane & 15;

    // XCD-bijective block swizzle: nwg = 512 = 8 * 64
    const int bid = blockIdx.x;
    const int id  = (bid & 7) * 64 + (bid >> 3);
    const int bRowM = (id >> 4) * 256;   // 32 M-tiles
    const int bColN = (id & 15) * 256;   // 16 N-tiles

    // ---- staging geometry ----
    const int srow   = tid >> 3;                     // 0..63 row within 64-row issue
    const int gchunk = (tid & 7) ^ (srow & 7);       // pre-swizzled global chunk
    const char* aSrc = (const char*)Xh + (size_t)(bRowM + srow) * (DIM_K * 2) + gchunk * 16;
    const char* bSrc = (const char*)Wh + (size_t)(bColN + srow) * (DIM_K * 2) + gchunk * 16;
    char* const ldsBase = smem;
    const int waveOff = wave * 1024;                 // wave-uniform LDS base part

#define STAGE_A(bufsel, h, dk) do {                                                             \
    _Pragma("unroll")                                                                           \
    for (int i_ = 0; i_ < 2; ++i_)                                                              \
        __builtin_amdgcn_global_load_lds(                                                       \
            (const __attribute__((address_space(1))) void*)(                                    \
                aSrc + (size_t)((h) * 128 + i_ * 64) * (DIM_K * 2) + (dk) * 128),               \
            (__attribute__((address_space(3))) void*)(                                          \
                ldsBase + (bufsel) * 32768 + ((h) * 128 + i_ * 64) * 128 + waveOff),            \
            16, 0, 0);                                                                          \
} while (0)
#define STAGE_B(bufsel, h, dk) do {                                                             \
    _Pragma("unroll")                                                                           \
    for (int i_ = 0; i_ < 2; ++i_)                                                              \
        __builtin_amdgcn_global_load_lds(                                                       \
            (const __attribute__((address_space(1))) void*)(                                    \
                bSrc + (size_t)((h) * 128 + i_ * 64) * (DIM_K * 2) + (dk) * 128),               \
            (__attribute__((address_space(3))) void*)(                                          \
                ldsBase + 65536 + (bufsel) * 32768 + ((h) * 128 + i_ * 64) * 128 + waveOff),    \
            16, 0, 0);                                                                          \
} while (0)

    // ---- compute-side LDS read bases ----
    const int swz = r & 7;
    const char* const aRd = smem + (wm * 64 + r) * 128;            // A half0 row base
    const char* const bRd = smem + 65536 + (wn * 32 + r) * 128;    // B half0 row base
    const int ck0 = ((0 * 4 + q) ^ swz) * 16;
    const int ck1 = ((1 * 4 + q) ^ swz) * 16;

    f32x4 acc[2][2][4][2] = {};   // [mhalf][nhalf][im 0..3 within 64][in 0..1]
    f16x8 aLo[2][2], aHi[2][2], b0[2][2], b1[2][2];

// frag read-issue macros (dst written AFTER its last use in program order)
#define RD_ALO(base, blkoff) do {                                        \
    aLo[0][0] = *(const f16x8*)((base) + (blkoff) + 0 * 2048 + ck0);     \
    aLo[0][1] = *(const f16x8*)((base) + (blkoff) + 0 * 2048 + ck1);     \
    aLo[1][0] = *(const f16x8*)((base) + (blkoff) + 1 * 2048 + ck0);     \
    aLo[1][1] = *(const f16x8*)((base) + (blkoff) + 1 * 2048 + ck1);     \
} while (0)
#define RD_AHI(base, blkoff) do {                                        \
    aHi[0][0] = *(const f16x8*)((base) + (blkoff) + 2 * 2048 + ck0);     \
    aHi[0][1] = *(const f16x8*)((base) + (blkoff) + 2 * 2048 + ck1);     \
    aHi[1][0] = *(const f16x8*)((base) + (blkoff) + 3 * 2048 + ck0);     \
    aHi[1][1] = *(const f16x8*)((base) + (blkoff) + 3 * 2048 + ck1);     \
} while (0)
#define RD_B0(base) do {                                                 \
    b0[0][0] = *(const f16x8*)((base) + 0 * 2048 + ck0);                 \
    b0[0][1] = *(const f16x8*)((base) + 0 * 2048 + ck1);                 \
    b0[1][0] = *(const f16x8*)((base) + 1 * 2048 + ck0);                 \
    b0[1][1] = *(const f16x8*)((base) + 1 * 2048 + ck1);                 \
} while (0)
#define RD_B1(base) do {                                                 \
    b1[0][0] = *(const f16x8*)((base) + 16384 + 0 * 2048 + ck0);         \
    b1[0][1] = *(const f16x8*)((base) + 16384 + 0 * 2048 + ck1);         \
    b1[1][0] = *(const f16x8*)((base) + 16384 + 1 * 2048 + ck0);         \
    b1[1][1] = *(const f16x8*)((base) + 16384 + 1 * 2048 + ck1);         \
} while (0)
// 8-MFMA sub-cluster: im pair {p,p+1} x in{0,1} x kk{0,1}
#define MM8(mh, nh, A, bb, p) do {                                       \
    _Pragma("unroll")                                                    \
    for (int i_ = 0; i_ < 2; ++i_)                                       \
        _Pragma("unroll")                                                \
        for (int n_ = 0; n_ < 2; ++n_)                                   \
            _Pragma("unroll")                                            \
            for (int k_ = 0; k_ < 2; ++k_)                               \
                acc[mh][nh][(p) + i_][n_] =                              \
                    __builtin_amdgcn_mfma_f32_16x16x32_f16(              \
                        A[i_][k_], bb[n_][k_], acc[mh][nh][(p) + i_][n_],\
                        0, 0, 0);                                        \
} while (0)

    // ---- prologue: stage kt0 fully (8 loads), then kt1 fully (8 loads) ----
    STAGE_A(0, 0, 0); STAGE_A(0, 1, 0); STAGE_B(0, 0, 0); STAGE_B(0, 1, 0);
    STAGE_A(1, 0, 1); STAGE_A(1, 1, 1); STAGE_B(1, 0, 1); STAGE_B(1, 1, 1);
    asm volatile("s_waitcnt vmcnt(8)" ::: "memory");   // kt0's 8 landed
    __builtin_amdgcn_s_barrier();
    __builtin_amdgcn_sched_barrier(0);
    // preload kt0's p0 frags (buffer 0)
    RD_B0(bRd);
    RD_ALO(aRd, 0);
    RD_AHI(aRd, 0);

#pragma unroll 2
    for (int kt = 0; kt < 64; ++kt) {
        const int cur = kt & 1, nxt = cur ^ 1;
        const char* const aC = aRd + cur * 32768;
        const char* const bC = bRd + cur * 32768;
        const char* const aN = aRd + nxt * 32768;
        const char* const bN = bRd + nxt * 32768;

        // ---------- p0 ----------
        asm volatile("s_waitcnt lgkmcnt(0)" ::: "memory");  // b0,aLo,aHi ready
        __builtin_amdgcn_sched_barrier(0);
        RD_B1(bC);                                   // for p1/p3
        __builtin_amdgcn_s_setprio(1);
        MM8(0, 0, aLo, b0, 0);
        MM8(0, 0, aHi, b0, 2);
        __builtin_amdgcn_s_setprio(0);
        __builtin_amdgcn_sched_barrier(0);
        __builtin_amdgcn_s_barrier();
        __builtin_amdgcn_sched_barrier(0);

        // ---------- p1 ----------
        asm volatile("s_waitcnt lgkmcnt(0)" ::: "memory");  // b1 ready
        __builtin_amdgcn_sched_barrier(0);
        __builtin_amdgcn_s_setprio(1);
        MM8(0, 1, aLo, b1, 0);
        __builtin_amdgcn_s_setprio(0);
        RD_ALO(aC, 16384);                           // reload: blk1 im01
        __builtin_amdgcn_s_setprio(1);
        MM8(0, 1, aHi, b1, 2);
        __builtin_amdgcn_s_setprio(0);
        RD_AHI(aC, 16384);                           // reload: blk1 im23
        if (kt < 62) { STAGE_A(cur, 0, 2); STAGE_B(cur, 0, 2); }
        __builtin_amdgcn_sched_barrier(0);
        __builtin_amdgcn_s_barrier();
        __builtin_amdgcn_sched_barrier(0);

        // ---------- p2 ----------
        asm volatile("s_waitcnt lgkmcnt(0)" ::: "memory");  // aLo',aHi' ready
        __builtin_amdgcn_sched_barrier(0);
        __builtin_amdgcn_s_setprio(1);
        MM8(1, 0, aLo, b0, 0);
        MM8(1, 0, aHi, b0, 2);
        __builtin_amdgcn_s_setprio(0);
        if (kt < 62) STAGE_B(cur, 1, 2);
        if (kt < 62) {
            asm volatile("s_waitcnt vmcnt(6)" ::: "memory");  // kt+1's 8 landed
        } else {
            asm volatile("s_waitcnt vmcnt(0)" ::: "memory");  // tail drain
        }
        __builtin_amdgcn_sched_barrier(0);
        __builtin_amdgcn_s_barrier();      // after this: kt+1 LDS data visible to all
        __builtin_amdgcn_sched_barrier(0);

        // ---------- p3 ----------
        if (kt < 63) RD_B0(bN);                      // next tile's b0 (slot dead)
        __builtin_amdgcn_s_setprio(1);
        MM8(1, 1, aLo, b1, 0);
        __builtin_amdgcn_s_setprio(0);
        if (kt < 63) RD_ALO(aN, 0);                  // next tile's blk0 im01
        __builtin_amdgcn_s_setprio(1);
        MM8(1, 1, aHi, b1, 2);
        __builtin_amdgcn_s_setprio(0);
        if (kt < 63) RD_AHI(aN, 0);                  // next tile's blk0 im23
        if (kt < 62) STAGE_A(cur, 1, 2);
        __builtin_amdgcn_sched_barrier(0);
        __builtin_amdgcn_s_barrier();
        __builtin_amdgcn_sched_barrier(0);

        aSrc += 128;   // advance one K-tile (64 halves)
        bSrc += 128;
    }

    // ---- epilogue: C/D layout col=lane&15, row=(lane>>4)*4+reg; bias folded ----
#pragma unroll
    for (int nh = 0; nh < 2; ++nh) {
#pragma unroll
        for (int in = 0; in < 2; ++in) {
            const int col = bColN + nh * 128 + wn * 32 + in * 16 + r;
            const float bia = B1[col] - B2[col];
#pragma unroll
            for (int mh = 0; mh < 2; ++mh) {
#pragma unroll
                for (int im = 0; im < 4; ++im) {
                    const int row0 = bRowM + mh * 128 + wm * 64 + im * 16 + q * 4;
                    const f32x4 v = acc[mh][nh][im][in];
#pragma unroll
                    for (int j = 0; j < 4; ++j)
                        C[(size_t)(row0 + j) * DIM_N + col] = v[j] + bia;
                }
            }
        }
    }
#undef STAGE_A
#undef STAGE_B
#undef RD_ALO
#undef RD_AHI
#undef RD_B0
#undef RD_B1
#undef MM8
}

// ---------------- launch ----------------

extern "C" void kernel_launch(void* const* d_in, const int* in_sizes, int n_in,
                              void* d_out, int out_size, void* d_ws, size_t ws_size,
                              hipStream_t stream) {
    const float* x  = (const float*)d_in[0];
    const float* W1 = (const float*)d_in[1];
    const float* W2 = (const float*)d_in[2];
    const float* b1 = (const float*)d_in[3];
    const float* b2 = (const float*)d_in[4];
    float* out = (float*)d_out;

    // workspace layout: Xh (64 MiB) | Wh (32 MiB)
    _Float16* Xh = (_Float16*)d_ws;
    _Float16* Wh = (_Float16*)((char*)d_ws + (size_t)67108864);
    (void)ws_size; (void)in_sizes; (void)n_in; (void)out_size;

    cvt_fused<<<2048, 256, 0, stream>>>((const float4*)x, (const float4*)W1,
                                        (const float4*)W2, (f16x8*)Xh, (f16x8*)Wh);

    // GEMM: 512 blocks of 512 threads, 256x256 tiles (32 M-tiles x 16 N-tiles)
    ternary_gemm<<<512, 512, 0, stream>>>(Xh, Wh, b1, b2, out);
}